// Round 4
// baseline (393.809 us; speedup 1.0000x reference)
//
#include <hip/hip_runtime.h>
#include <hip/hip_bf16.h>
#include <stdint.h>

// BitLinear: out[t,o] = (sum_i clip(rint(x[t,i]/xs),-128,127) * clip(rint(w[o,i]/ws),-1,1)) * xs*ws
// M=8192, N=4096, K=4096.
// R3: fatter wave tile to fix LDS/MFMA imbalance. R2 analysis: ds_read_b128 runs
// at 85 B/cyc/CU (m134 structural rate; the 4 extra cyc/read in SQ_LDS_BANK_CONFLICT
// is intrinsic, not a fixable conflict). With 2x2 wave tiles (1 read/MFMA) LDS time
// (82us) > MFMA time (62us) and they serialize. Wave tile 128x64 = 4x2 of 32x32:
// 6 reads / 8 MFMAs = 0.75 -> LDS 62us == MFMA 62us, balanced.
// Block 256x128 (4 waves 2x2), LDS 48KB, acc=128 VGPRs, ~2 blocks/CU.

typedef int  int4v  __attribute__((ext_vector_type(4)));
typedef int  int16v __attribute__((ext_vector_type(16)));

typedef __attribute__((address_space(1))) void gvoid;
typedef __attribute__((address_space(3))) void lvoid;

#define M_DIM 8192
#define N_DIM 4096
#define K_DIM 4096

#define BM 256
#define BN 128
#define BK 128   // K-bytes per tile iteration (one full 32-bank frame per row)

// ---------------- quantize: fp32 -> int8 ----------------
__global__ __launch_bounds__(256) void quant_kernel(
    const float* __restrict__ in, int8_t* __restrict__ out,
    const float* __restrict__ scale_ptr, float lo, float hi, long n) {
  long i = ((long)blockIdx.x * blockDim.x + threadIdx.x) * 16;
  if (i >= n) return;
  float s = scale_ptr[0];
  float4 a = *(const float4*)(in + i);
  float4 b = *(const float4*)(in + i + 4);
  float4 c = *(const float4*)(in + i + 8);
  float4 d = *(const float4*)(in + i + 12);
  float v[16] = {a.x, a.y, a.z, a.w, b.x, b.y, b.z, b.w,
                 c.x, c.y, c.z, c.w, d.x, d.y, d.z, d.w};
  union { int8_t c[16]; int4 q; } u;
#pragma unroll
  for (int t = 0; t < 16; ++t) {
    float q = rintf(v[t] / s);           // round-half-even, matches np.round
    q = fminf(fmaxf(q, lo), hi);
    u.c[t] = (int8_t)q;
  }
  *(int4*)(out + i) = u.q;
}

// ---------------- GEMM: C[M,N] = A[M,K] * B[N,K]^T (i8 -> i32), scaled ----------------
// 256 threads = 4 waves arranged 2x2; wave tile 128x64 = 4x2 of 32x32x32 MFMA.
__global__ __launch_bounds__(256, 2) void gemm_bt(
    const int8_t* __restrict__ A,   // [M,K] i8 (x_q)
    const int8_t* __restrict__ B,   // [N,K] i8 (w_q)
    float* __restrict__ C,          // [M,N]
    const float* __restrict__ ws_ptr, const float* __restrict__ xs_ptr) {
  __shared__ __attribute__((aligned(16))) char smem[BM * BK + BN * BK];  // 32KB + 16KB
  char* sA = smem;
  char* sB = smem + BM * BK;

  const int tid  = threadIdx.x;
  const int wave = tid >> 6;
  const int lane = tid & 63;
  const int wr   = wave >> 1;     // wave row (0..1) -> 128-row strip of C
  const int wc   = wave & 1;      // wave col (0..1) -> 64-col strip of C
  const int r    = lane & 31;     // MFMA row/col index within 32-tile
  const int half = lane >> 5;     // 0..1 -> k-half of fragment

  const long m0 = (long)blockIdx.y * BM;
  const long n0 = (long)blockIdx.x * BN;

  // ---- staging addressing ----
  // per global_load_lds: one wave covers 1024B = 8 rows of 128B.
  // lane l -> row (l>>3), LDS chunk (l&7); source chunk = (l&7) ^ (row&7)
  const int lrow   = lane >> 3;
  const int schunk = ((lane & 7) ^ lrow) * 16;     // swizzled source byte offset
  // A: wave covers 64 rows (8 loads); B: wave covers 32 rows (4 loads)
  const int8_t* gA = A + (m0 + wave * 64 + lrow) * K_DIM + schunk;
  const int8_t* gB = B + (n0 + wave * 32 + lrow) * K_DIM + schunk;
  char* lA = sA + wave * 8192;   // + t*1024 (HW appends lane*16)
  char* lB = sB + wave * 4096;

  int16v acc[4][2] = {};

  for (int k0 = 0; k0 < K_DIM; k0 += BK) {
#pragma unroll
    for (int t = 0; t < 8; ++t)
      __builtin_amdgcn_global_load_lds((gvoid*)(gA + t * 8 * K_DIM),
                                       (lvoid*)(lA + t * 1024), 16, 0, 0);
#pragma unroll
    for (int t = 0; t < 4; ++t)
      __builtin_amdgcn_global_load_lds((gvoid*)(gB + t * 8 * K_DIM),
                                       (lvoid*)(lB + t * 1024), 16, 0, 0);
    gA += BK;
    gB += BK;
    __syncthreads();   // drains vmcnt (global_load_lds) + workgroup barrier

    // fragment rows: A row = wr*128 + mb*32 + r; B row = wc*64 + nb*32 + r.
    // row&7 == lane&7 for all of them (offsets are multiples of 32).
#pragma unroll
    for (int ks = 0; ks < 4; ++ks) {
      const int co = (((ks * 2 + half) ^ (lane & 7)) * 16);
      int4v af[4], bf[2];
#pragma unroll
      for (int mb = 0; mb < 4; ++mb)
        af[mb] = *(const int4v*)(sA + (wr * 128 + mb * 32 + r) * BK + co);
#pragma unroll
      for (int nb = 0; nb < 2; ++nb)
        bf[nb] = *(const int4v*)(sB + (wc * 64 + nb * 32 + r) * BK + co);
#pragma unroll
      for (int mb = 0; mb < 4; ++mb)
#pragma unroll
        for (int nb = 0; nb < 2; ++nb)
          acc[mb][nb] = __builtin_amdgcn_mfma_i32_32x32x32_i8(af[mb], bf[nb], acc[mb][nb], 0, 0, 0);
    }

    __syncthreads();   // protect LDS from next iteration's overwrite
  }

  // epilogue: 32x32 C/D layout col=lane&31, row=(reg&3)+8*(reg>>2)+4*(lane>>5)
  const float s = ws_ptr[0] * xs_ptr[0];
#pragma unroll
  for (int mb = 0; mb < 4; ++mb) {
#pragma unroll
    for (int nb = 0; nb < 2; ++nb) {
      const long col = n0 + wc * 64 + nb * 32 + r;
      const long rowbase = m0 + wr * 128 + mb * 32 + 4 * half;
#pragma unroll
      for (int reg = 0; reg < 16; ++reg) {
        const long row = rowbase + (reg & 3) + 8 * (reg >> 2);
        C[row * N_DIM + col] = (float)acc[mb][nb][reg] * s;
      }
    }
  }
}

extern "C" void kernel_launch(void* const* d_in, const int* in_sizes, int n_in,
                              void* d_out, int out_size, void* d_ws, size_t ws_size,
                              hipStream_t stream) {
  const float* x  = (const float*)d_in[0];   // [8192,4096]
  const float* w  = (const float*)d_in[1];   // [4096,4096]
  const float* ws = (const float*)d_in[2];   // [1]
  const float* xs = (const float*)d_in[3];   // [1]
  float* out = (float*)d_out;

  int8_t* xq = (int8_t*)d_ws;
  int8_t* wq = (int8_t*)d_ws + (size_t)M_DIM * K_DIM;

  const long n_x = (long)M_DIM * K_DIM;
  const long n_w = (long)N_DIM * K_DIM;

  quant_kernel<<<(n_x / 16 + 255) / 256, 256, 0, stream>>>(x, xq, xs, -128.f, 127.f, n_x);
  quant_kernel<<<(n_w / 16 + 255) / 256, 256, 0, stream>>>(w, wq, ws, -1.f, 1.f, n_w);

  dim3 grid(N_DIM / BN, M_DIM / BM);   // 32 x 32 = 1024 blocks
  gemm_bt<<<grid, 256, 0, stream>>>(xq, wq, out, ws, xs);
}